// Round 19
// baseline (314.309 us; speedup 1.0000x reference)
//
#include <hip/hip_runtime.h>
#include <stdint.h>

#define N_NODES 32768
#define N_EDGES 524288
#define NODE_MASK (N_NODES - 1)

typedef __attribute__((ext_vector_type(4))) float f32x4;
typedef __attribute__((ext_vector_type(8))) _Float16 f16x8;
typedef unsigned short ushort_t;

// split f32[8] -> (hi, lo) f16x8 planes; hi = f16(x), lo = f16(x - hi).
__device__ __forceinline__ void split8f(const float* __restrict__ p,
                                        f16x8* H, f16x8* L) {
  f16x8 h, lo;
#pragma unroll
  for (int i = 0; i < 8; ++i) {
    float x = p[i];
    _Float16 hh = (_Float16)x;        // RNE
    float r = x - (float)hh;          // exact residual
    h[i] = hh;
    lo[i] = (_Float16)r;
  }
  *H = h; *L = lo;
}

// ---------------- threefry2x32 (Threefry-20, partitionable mode) ------------
__device__ __forceinline__ uint32_t rotl32(uint32_t v, int r) {
  return (v << r) | (v >> (32 - r));
}

__device__ __forceinline__ void threefry2x32(uint32_t k0, uint32_t k1,
                                             uint32_t x0, uint32_t x1,
                                             uint32_t* o0, uint32_t* o1) {
  uint32_t k2 = k0 ^ k1 ^ 0x1BD11BDAu;
  x0 += k0; x1 += k1;
  x0 += x1; x1 = rotl32(x1, 13); x1 ^= x0;
  x0 += x1; x1 = rotl32(x1, 15); x1 ^= x0;
  x0 += x1; x1 = rotl32(x1, 26); x1 ^= x0;
  x0 += x1; x1 = rotl32(x1,  6); x1 ^= x0;
  x0 += k1; x1 += k2 + 1u;
  x0 += x1; x1 = rotl32(x1, 17); x1 ^= x0;
  x0 += x1; x1 = rotl32(x1, 29); x1 ^= x0;
  x0 += x1; x1 = rotl32(x1, 16); x1 ^= x0;
  x0 += x1; x1 = rotl32(x1, 24); x1 ^= x0;
  x0 += k2; x1 += k0 + 2u;
  x0 += x1; x1 = rotl32(x1, 13); x1 ^= x0;
  x0 += x1; x1 = rotl32(x1, 15); x1 ^= x0;
  x0 += x1; x1 = rotl32(x1, 26); x1 ^= x0;
  x0 += x1; x1 = rotl32(x1,  6); x1 ^= x0;
  x0 += k0; x1 += k1 + 3u;
  x0 += x1; x1 = rotl32(x1, 17); x1 ^= x0;
  x0 += x1; x1 = rotl32(x1, 29); x1 ^= x0;
  x0 += x1; x1 = rotl32(x1, 16); x1 ^= x0;
  x0 += x1; x1 = rotl32(x1, 24); x1 ^= x0;
  x0 += k1; x1 += k2 + 4u;
  x0 += x1; x1 = rotl32(x1, 13); x1 ^= x0;
  x0 += x1; x1 = rotl32(x1, 15); x1 ^= x0;
  x0 += x1; x1 = rotl32(x1, 26); x1 ^= x0;
  x0 += x1; x1 = rotl32(x1,  6); x1 ^= x0;
  x0 += k2; x1 += k0 + 5u;
  *o0 = x0; *o1 = x1;
}

__device__ __forceinline__ float bits_to_normal(uint32_t b) {
  uint32_t fb = (b >> 9) | 0x3F800000u;
  float f = __uint_as_float(fb) - 1.0f;          // [0,1)
  const float LO = -0.99999994f;
  float u = f * 2.0f + LO;
  u = fmaxf(LO, u);
  double zd = 1.4142135623730951 * erfinv((double)u);
  return (float)zd;
}

// ---------------- zero helpers -----------------------------------------------
__global__ void k_zero(int* __restrict__ p, int n) {
  for (int i = blockIdx.x * blockDim.x + threadIdx.x; i < n;
       i += gridDim.x * blockDim.x)
    p[i] = 0;
}

// zero mg cols 64..127 for all nodes (layer-0 upper half)
__global__ void k_zmg(_Float16* __restrict__ mg) {
  int i = blockIdx.x * 256 + threadIdx.x;     // 262144 f16x8 chunks / 8
  if (i >= N_NODES * 8) return;
  int n = i >> 3, cg = i & 7;
  f16x8 zz;
#pragma unroll
  for (int j = 0; j < 8; ++j) zz[j] = (_Float16)0.f;
  *(f16x8*)&mg[n * 128 + 64 + cg * 8] = zz;
}

// ---------------- CSR build (plain, parallel scan) --------------------------
__global__ void k_hist(const int* __restrict__ ei, int* __restrict__ counts) {
  for (int e = blockIdx.x * blockDim.x + threadIdx.x; e < N_EDGES;
       e += gridDim.x * blockDim.x)
    atomicAdd(&counts[ei[N_EDGES + e] & NODE_MASK], 1);
}

// per-block inclusive scan of 1024 coalesced counts; block sums out
__global__ __launch_bounds__(1024) void k_scanA(const int* __restrict__ counts,
                                                int* __restrict__ row_ptr,
                                                int* __restrict__ bsum) {
  __shared__ int part[1024];
  int t = threadIdx.x;
  int node = blockIdx.x * 1024 + t;
  part[t] = counts[node];
  __syncthreads();
  for (int off = 1; off < 1024; off <<= 1) {
    int add = (t >= off) ? part[t - off] : 0;
    __syncthreads();
    part[t] += add;
    __syncthreads();
  }
  row_ptr[node] = part[t];               // block-local inclusive
  if (t == 1023) bsum[blockIdx.x] = part[1023];
}

// apply block offsets -> exclusive global prefix; zero cursors; total
__global__ __launch_bounds__(1024) void k_scanB(const int* __restrict__ bsum,
                                                int* __restrict__ row_ptr,
                                                int* __restrict__ counts) {
  __shared__ int sb[32];
  int t = threadIdx.x, b = blockIdx.x;
  if (t < 32) sb[t] = bsum[t];
  __syncthreads();
  int boff = 0;
#pragma unroll
  for (int i = 0; i < 32; ++i) boff += (i < b) ? sb[i] : 0;
  int node = b * 1024 + t;
  int incl = row_ptr[node];
  int cnt = counts[node];
  row_ptr[node] = boff + incl - cnt;     // exclusive global prefix
  counts[node] = 0;                      // cursor init for k_fill
  if (b == 31 && t == 1023) {
    int tot = 0;
#pragma unroll
    for (int i = 0; i < 32; ++i) tot += sb[i];
    row_ptr[N_NODES] = tot;
  }
}

__global__ void k_fill(const int* __restrict__ ei, const int* __restrict__ row_ptr,
                       int* __restrict__ cursor, int* __restrict__ srcs) {
  for (int e = blockIdx.x * blockDim.x + threadIdx.x; e < N_EDGES;
       e += gridDim.x * blockDim.x) {
    int d = ei[N_EDGES + e] & NODE_MASK;
    int pos = row_ptr[d] + atomicAdd(&cursor[d], 1);
    srcs[pos] = ei[e] & NODE_MASK;
  }
}

// ---------------- merged prep (blocks 0..767) + lin0 (768..8959) ------------
__global__ __launch_bounds__(256) void k_preplin0(
    const float* __restrict__ G, const float* __restrict__ w_ih,
    const float* __restrict__ w_hh,
    _Float16* __restrict__ WcF, _Float16* __restrict__ whhF,
    float* __restrict__ z,
    const float* __restrict__ x, const float* __restrict__ lw,
    float* __restrict__ hf, _Float16* __restrict__ h16) {
  __shared__ float sw[64][33];
  __shared__ float sx[4][32];
  int b = blockIdx.x, t = threadIdx.x;
  if (b < 768) {
    int i = b * 256 + t;
    if (i < 4 * 384 * 128) {
      int L = i / (384 * 128), r = i % (384 * 128);
      int c = r >> 7, k = r & 127;
      const float* g  = G + L * 16384 + k * 128;
      const float* wv = w_ih + c * 128;
      float acc = 0.f;
#pragma unroll 8
      for (int j = 0; j < 128; ++j) acc += g[j] * wv[j];
      WcF[i] = (_Float16)acc;
    }
    if (i < 384 * 128) whhF[i] = (_Float16)w_hh[i];
    if (i < 32640) {
      uint32_t o0, o1;
      threefry2x32(0u, 123u, 0u, (uint32_t)i, &o0, &o1);
      z[i] = bits_to_normal(o0 ^ o1);
    }
    return;
  }
  // ---- lin0 path ----
  int node0 = (b - 768) * 4;
  for (int e = t; e < 64 * 32; e += 256) sw[e >> 5][e & 31] = lw[e];
  if (t < 128) sx[t >> 5][t & 31] = x[node0 * 32 + t];
  __syncthreads();
  int c = t & 63, nl = t >> 6;
  float acc = 0.f;
#pragma unroll
  for (int k = 0; k < 32; ++k) acc += sx[nl][k] * sw[c][k];
  float s = 1.f / (1.f + expf(-acc));
  int n = node0 + nl;
  hf[n * 128 + c] = s;
  hf[n * 128 + 64 + c] = 0.f;
  h16[n * 128 + c] = (_Float16)s;
  h16[n * 128 + 64 + c] = (_Float16)0.f;
}

// ---------------- segment-sum gather, COLUMN-HALF pass ----------------------
// Per pass, all waves read only h16[:, colBase..colBase+63] (4 MB working
// set == per-XCD L2). 8 edges x 8 colgroups x 16 B/lane.
__global__ void k_agg(const _Float16* __restrict__ h16,
                      _Float16* __restrict__ mg,
                      const int* __restrict__ row_ptr, const int* __restrict__ srcs,
                      int colBase) {
  int wid = (blockIdx.x * blockDim.x + threadIdx.x) >> 6;
  int lane = threadIdx.x & 63;
  if (wid >= N_NODES) return;
  int beg = row_ptr[wid], end = row_ptr[wid + 1];
  int cg = lane & 7, eg = lane >> 3;
  float acc[8];
#pragma unroll
  for (int i = 0; i < 8; ++i) acc[i] = 0.f;
#pragma unroll 2
  for (int e = beg + eg; e < end; e += 8) {
    int s = srcs[e];
    f16x8 v = *(const f16x8*)&h16[s * 128 + colBase + cg * 8];
#pragma unroll
    for (int i = 0; i < 8; ++i) acc[i] += (float)v[i];
  }
#pragma unroll
  for (int i = 0; i < 8; ++i) {
    acc[i] += __shfl_xor(acc[i], 8);
    acc[i] += __shfl_xor(acc[i], 16);
    acc[i] += __shfl_xor(acc[i], 32);
  }
  if (eg == 0) {
    f16x8 o;
#pragma unroll
    for (int i = 0; i < 8; ++i) o[i] = (_Float16)acc[i];
    *(f16x8*)&mg[wid * 128 + colBase + cg * 8] = o;
  }
}

// ---------------- fused GRU via f16 MFMA (16 nodes/wave) --------------------
// gi = mg(f16) @ Wc^T (+b_ih); gh = h(2-term f16) @ w_hh^T (+b_hh).
__global__ __launch_bounds__(256, 2) void k_gru_mfma(
    const _Float16* __restrict__ mg,
    float* __restrict__ hf, _Float16* __restrict__ h16,
    const _Float16* __restrict__ WcF, const _Float16* __restrict__ whhF,
    const float* __restrict__ b_ih, const float* __restrict__ b_hh,
    int writeShadow) {
  __shared__ __align__(16) char smem[24576];  // 6 slices x 4 KB
  int t = threadIdx.x;
  int w = t >> 6, l = t & 63;
  int node0 = blockIdx.x * 64 + w * 16;
  int ar = l & 15, hi = l >> 4, ak = hi * 8;
  f16x8 am[4], ahH[4], ahL[4];
#pragma unroll
  for (int kk = 0; kk < 4; ++kk) {
    int o = (node0 + ar) * 128 + kk * 32 + ak;
    am[kk] = *(const f16x8*)&mg[o];
    split8f(&hf[o], &ahH[kk], &ahL[kk]);
  }
  const _Float16* pq[6];
#pragma unroll
  for (int q = 0; q < 6; ++q) {
    int i = (q * 4 + w) * 64 + l;
    int s = i >> 8, r = (i >> 4) & 15, gl = i & 15;
    int gsrc = gl ^ (r & 7);
    int mtx = s / 3, gate = s % 3;
    const _Float16* base = mtx ? whhF : WcF;
    pq[q] = base + (gate * 128 + r) * 128 + gsrc * 8;
  }
  const char* lds = (const char*)smem;
  for (int ct = 0; ct < 8; ++ct) {
    int c0 = ct * 16;
#pragma unroll
    for (int q = 0; q < 6; ++q) {
      __builtin_amdgcn_global_load_lds(
          (const __attribute__((address_space(1))) void*)(pq[q] + c0 * 128),
          (__attribute__((address_space(3))) void*)(smem + (q * 4 + w) * 1024),
          16, 0, 0);
    }
    int col = c0 + ar;
    float hp[4];
#pragma unroll
    for (int j = 0; j < 4; ++j)
      hp[j] = hf[(node0 + hi * 4 + j) * 128 + col];
    __syncthreads();
    f32x4 air = {0.f,0.f,0.f,0.f}, aiz = air, ain = air;
    f32x4 ahr = air, ahz = air, ahn = air;
    int rbase = ar * 256;
    int rsw = (ar & 7) << 4;
#pragma unroll
    for (int kk = 0; kk < 4; ++kk) {
      int bin = rbase + ((kk * 64 + hi * 16) ^ rsw);
      f16x8 W0 = *(const f16x8*)(lds + 0 * 4096 + bin);
      f16x8 W1 = *(const f16x8*)(lds + 1 * 4096 + bin);
      f16x8 W2 = *(const f16x8*)(lds + 2 * 4096 + bin);
      f16x8 W3 = *(const f16x8*)(lds + 3 * 4096 + bin);
      f16x8 W4 = *(const f16x8*)(lds + 4 * 4096 + bin);
      f16x8 W5 = *(const f16x8*)(lds + 5 * 4096 + bin);
      air = __builtin_amdgcn_mfma_f32_16x16x32_f16(am[kk],  W0, air, 0, 0, 0);
      aiz = __builtin_amdgcn_mfma_f32_16x16x32_f16(am[kk],  W1, aiz, 0, 0, 0);
      ain = __builtin_amdgcn_mfma_f32_16x16x32_f16(am[kk],  W2, ain, 0, 0, 0);
      ahr = __builtin_amdgcn_mfma_f32_16x16x32_f16(ahH[kk], W3, ahr, 0, 0, 0);
      ahr = __builtin_amdgcn_mfma_f32_16x16x32_f16(ahL[kk], W3, ahr, 0, 0, 0);
      ahz = __builtin_amdgcn_mfma_f32_16x16x32_f16(ahH[kk], W4, ahz, 0, 0, 0);
      ahz = __builtin_amdgcn_mfma_f32_16x16x32_f16(ahL[kk], W4, ahz, 0, 0, 0);
      ahn = __builtin_amdgcn_mfma_f32_16x16x32_f16(ahH[kk], W5, ahn, 0, 0, 0);
      ahn = __builtin_amdgcn_mfma_f32_16x16x32_f16(ahL[kk], W5, ahn, 0, 0, 0);
    }
    float bir = b_ih[col], biz = b_ih[128 + col], bin = b_ih[256 + col];
    float bhr = b_hh[col], bhz = b_hh[128 + col], bhn = b_hh[256 + col];
#pragma unroll
    for (int j = 0; j < 4; ++j) {
      int idx = (node0 + hi * 4 + j) * 128 + col;
      float gr = air[j] + bir + ahr[j] + bhr;
      float gz = aiz[j] + biz + ahz[j] + bhz;
      float r  = 1.f / (1.f + expf(-gr));
      float zg = 1.f / (1.f + expf(-gz));
      float nn = tanhf(ain[j] + bin + r * (ahn[j] + bhn));
      float hn = (1.f - zg) * nn + zg * hp[j];
      hf[idx] = hn;
      if (writeShadow) h16[idx] = (_Float16)hn;
    }
    __syncthreads();
  }
}

// ---------------- heads (f32 hf) ---------------------------------------------
__global__ __launch_bounds__(256) void k_musig(const float* __restrict__ hf,
                                               const float* __restrict__ w1,
                                               const float* __restrict__ b1,
                                               const float* __restrict__ w2,
                                               const float* __restrict__ b2,
                                               float* __restrict__ mu,
                                               float* __restrict__ sigma) {
  int t = threadIdx.x;
  int lane = t & 63, wv = t >> 6;
  int n = blockIdx.x * 4 + wv;
  float2 hv = *(const float2*)&hf[n * 128 + lane * 2];
  hv.x = fmaxf(hv.x, 0.f); hv.y = fmaxf(hv.y, 0.f);
  float2 w1v = *(const float2*)&w1[lane * 2];
  float2 w2v = *(const float2*)&w2[lane * 2];
  float a = hv.x * w1v.x + hv.y * w1v.y;
  float b = hv.x * w2v.x + hv.y * w2v.y;
#pragma unroll
  for (int off = 32; off > 0; off >>= 1) {
    a += __shfl_down(a, off);
    b += __shfl_down(b, off);
  }
  if (lane == 0) {
    mu[n] = a + b1[0];
    float v = b + b2[0];
    sigma[n] = fmaxf(v, 0.f) + log1pf(expf(-fabsf(v)));
  }
}

// ---------------- sampler (fp64 internal): analytic Cholesky ----------------
__device__ __forceinline__ double dscan_incl(double v, volatile double* buf, int i,
                                             double* tot) {
  buf[i] = v;
  __syncthreads();
#pragma unroll
  for (int off = 1; off < 256; off <<= 1) {
    double add = (i >= off) ? buf[i - off] : 0.0;
    __syncthreads();
    buf[i] += add;
    __syncthreads();
  }
  double incl = buf[i];
  *tot = buf[255];
  __syncthreads();
  return incl;
}

__global__ __launch_bounds__(256) void k_sample(const float* __restrict__ mu,
                                                const float* __restrict__ sigma,
                                                const float* __restrict__ zbuf,
                                                float* __restrict__ out) {
  __shared__ double buf[256];
  __shared__ double lastd[2];
  int g = blockIdx.x, i = threadIdx.x;
  int n = (g << 8) + i;
  double sig = (double)sigma[n], muv = (double)mu[n];
  bool isLast = (i == 255);
  if (isLast) { lastd[0] = sig; lastd[1] = muv; }
  double s   = isLast ? 0.0 : sig;
  double mui = isLast ? 0.0 : muv;
  double tS, tM, tY, tX;
  double inclS = dscan_incl(s, buf, i, &tS);
  dscan_incl(mui, buf, i, &tM);
  double sigLast = lastd[0], muLast = lastd[1];
  double denom = tS + sigLast;
  double c = -muLast / sigLast;
  double pre = inclS - s;
  double suffix  = denom - pre;
  double suffix1 = suffix - s;
  double sigL = isLast ? 0.0 : sqrt(s * suffix1 / suffix);
  double cL   = isLast ? 0.0 : (-s / (suffix * sigL));
  double zv   = isLast ? 0.0 : (double)zbuf[g * 255 + i];
  double y = cL * zv;
  double inclY = dscan_incl(y, buf, i, &tY);
  double Pz = inclY - y;
  double rm = s * c + mui - s * (c * tS + tM) / denom;
  double X = rm + s * Pz + sigL * zv;
  if (isLast) X = 0.0;
  dscan_incl(X, buf, i, &tX);
  out[n] = (float)(isLast ? (0.0 - tX) : X);
}

// ---------------------------------------------------------------------------
extern "C" void kernel_launch(void* const* d_in, const int* in_sizes, int n_in,
                              void* d_out, int out_size, void* d_ws, size_t ws_size,
                              hipStream_t stream) {
  const float* x      = (const float*)d_in[0];
  const float* lin0_w = (const float*)d_in[1];
  const float* ggc_w  = (const float*)d_in[2];
  const float* w_ih   = (const float*)d_in[3];
  const float* w_hh   = (const float*)d_in[4];
  const float* b_ih   = (const float*)d_in[5];
  const float* b_hh   = (const float*)d_in[6];
  const float* lin1_w = (const float*)d_in[7];
  const float* lin1_b = (const float*)d_in[8];
  const float* lin2_w = (const float*)d_in[9];
  const float* lin2_b = (const float*)d_in[10];
  const int*   ei     = (const int*)d_in[11];
  float* out = (float*)d_out;

  char* ws = (char*)d_ws;
  float*     hf     = (float*)    (ws + 0);          // 16 MB
  _Float16*  h16    = (_Float16*) (ws + 16777216);   // 8 MB
  _Float16*  mg     = (_Float16*) (ws + 25165824);   // 8 MB (f16 hagg)
  _Float16*  WcF    = (_Float16*) (ws + 33554432);   // 384 KB
  _Float16*  whhF   = (_Float16*) (ws + 33947648);   // 96 KB
  float*     zbuf   = (float*)    (ws + 34045952);   // 128 KB [counts aliases]
  float*     mu     = (float*)    (ws + 34177024);   // 128 KB
  float*     sigma  = (float*)    (ws + 34308096);   // 128 KB
  int*       row_ptr= (int*)      (ws + 34439168);   // 128.5 KB slot
  int*       srcs   = (int*)      (ws + 34570752);   // 2 MB
  int*       bsum   = (int*)      (ws + 36667904);   // 128 B
  int*       counts = (int*)zbuf;                    // alias: CSR before k_preplin0
  const size_t WS_NEEDED = 36668032;                 // < proven 53477888
  if (ws_size < WS_NEEDED) return;

  // CSR build (parallel scan; counts re-zeroed by k_scanB for cursor use)
  k_zero<<<32, 256, 0, stream>>>(counts, N_NODES);
  k_hist<<<1024, 256, 0, stream>>>(ei, counts);
  k_scanA<<<32, 1024, 0, stream>>>(counts, row_ptr, bsum);
  k_scanB<<<32, 1024, 0, stream>>>(bsum, row_ptr, counts);
  k_fill<<<1024, 256, 0, stream>>>(ei, row_ptr, counts, srcs);

  k_preplin0<<<8960, 256, 0, stream>>>(ggc_w, w_ih, w_hh, WcF, whhF, zbuf,
                                       x, lin0_w, hf, h16);

  for (int L = 0; L < 4; ++L) {
    k_agg<<<8192, 256, 0, stream>>>(h16, mg, row_ptr, srcs, 0);
    if (L == 0) {
      k_zmg<<<1024, 256, 0, stream>>>(mg);      // upper half structurally zero
    } else {
      k_agg<<<8192, 256, 0, stream>>>(h16, mg, row_ptr, srcs, 64);
    }
    k_gru_mfma<<<512, 256, 0, stream>>>(mg, hf, h16,
                                        WcF + (size_t)L * 49152,
                                        whhF, b_ih, b_hh, L < 3 ? 1 : 0);
  }

  k_musig<<<8192, 256, 0, stream>>>(hf, lin1_w, lin1_b, lin2_w, lin2_b, mu, sigma);
  k_sample<<<128, 256, 0, stream>>>(mu, sigma, zbuf, out);
}

// Round 20
// 285.627 us; speedup vs baseline: 1.1004x; 1.1004x over previous
//
#include <hip/hip_runtime.h>
#include <stdint.h>

#define N_NODES 32768
#define N_EDGES 524288
#define NODE_MASK (N_NODES - 1)

typedef __attribute__((ext_vector_type(4))) float f32x4;
typedef __attribute__((ext_vector_type(8))) _Float16 f16x8;
typedef unsigned short ushort_t;

// split f32[8] -> (hi, lo) f16x8 planes; hi = f16(x), lo = f16(x - hi).
__device__ __forceinline__ void split8f(const float* __restrict__ p,
                                        f16x8* H, f16x8* L) {
  f16x8 h, lo;
#pragma unroll
  for (int i = 0; i < 8; ++i) {
    float x = p[i];
    _Float16 hh = (_Float16)x;        // RNE
    float r = x - (float)hh;          // exact residual
    h[i] = hh;
    lo[i] = (_Float16)r;
  }
  *H = h; *L = lo;
}

// ---------------- threefry2x32 (Threefry-20, partitionable mode) ------------
__device__ __forceinline__ uint32_t rotl32(uint32_t v, int r) {
  return (v << r) | (v >> (32 - r));
}

__device__ __forceinline__ void threefry2x32(uint32_t k0, uint32_t k1,
                                             uint32_t x0, uint32_t x1,
                                             uint32_t* o0, uint32_t* o1) {
  uint32_t k2 = k0 ^ k1 ^ 0x1BD11BDAu;
  x0 += k0; x1 += k1;
  x0 += x1; x1 = rotl32(x1, 13); x1 ^= x0;
  x0 += x1; x1 = rotl32(x1, 15); x1 ^= x0;
  x0 += x1; x1 = rotl32(x1, 26); x1 ^= x0;
  x0 += x1; x1 = rotl32(x1,  6); x1 ^= x0;
  x0 += k1; x1 += k2 + 1u;
  x0 += x1; x1 = rotl32(x1, 17); x1 ^= x0;
  x0 += x1; x1 = rotl32(x1, 29); x1 ^= x0;
  x0 += x1; x1 = rotl32(x1, 16); x1 ^= x0;
  x0 += x1; x1 = rotl32(x1, 24); x1 ^= x0;
  x0 += k2; x1 += k0 + 2u;
  x0 += x1; x1 = rotl32(x1, 13); x1 ^= x0;
  x0 += x1; x1 = rotl32(x1, 15); x1 ^= x0;
  x0 += x1; x1 = rotl32(x1, 26); x1 ^= x0;
  x0 += x1; x1 = rotl32(x1,  6); x1 ^= x0;
  x0 += k0; x1 += k1 + 3u;
  x0 += x1; x1 = rotl32(x1, 17); x1 ^= x0;
  x0 += x1; x1 = rotl32(x1, 29); x1 ^= x0;
  x0 += x1; x1 = rotl32(x1, 16); x1 ^= x0;
  x0 += x1; x1 = rotl32(x1, 24); x1 ^= x0;
  x0 += k1; x1 += k2 + 4u;
  x0 += x1; x1 = rotl32(x1, 13); x1 ^= x0;
  x0 += x1; x1 = rotl32(x1, 15); x1 ^= x0;
  x0 += x1; x1 = rotl32(x1, 26); x1 ^= x0;
  x0 += x1; x1 = rotl32(x1,  6); x1 ^= x0;
  x0 += k2; x1 += k0 + 5u;
  *o0 = x0; *o1 = x1;
}

__device__ __forceinline__ float bits_to_normal(uint32_t b) {
  uint32_t fb = (b >> 9) | 0x3F800000u;
  float f = __uint_as_float(fb) - 1.0f;          // [0,1)
  const float LO = -0.99999994f;
  float u = f * 2.0f + LO;
  u = fmaxf(LO, u);
  double zd = 1.4142135623730951 * erfinv((double)u);
  return (float)zd;
}

// ---------------- zero helper ------------------------------------------------
__global__ void k_zero(int* __restrict__ p, int n) {
  for (int i = blockIdx.x * blockDim.x + threadIdx.x; i < n;
       i += gridDim.x * blockDim.x)
    p[i] = 0;
}

// ---------------- CSR build (plain, parallel scan) --------------------------
__global__ void k_hist(const int* __restrict__ ei, int* __restrict__ counts) {
  for (int e = blockIdx.x * blockDim.x + threadIdx.x; e < N_EDGES;
       e += gridDim.x * blockDim.x)
    atomicAdd(&counts[ei[N_EDGES + e] & NODE_MASK], 1);
}

// per-block inclusive scan of 1024 coalesced counts; block sums out
__global__ __launch_bounds__(1024) void k_scanA(const int* __restrict__ counts,
                                                int* __restrict__ row_ptr,
                                                int* __restrict__ bsum) {
  __shared__ int part[1024];
  int t = threadIdx.x;
  int node = blockIdx.x * 1024 + t;
  part[t] = counts[node];
  __syncthreads();
  for (int off = 1; off < 1024; off <<= 1) {
    int add = (t >= off) ? part[t - off] : 0;
    __syncthreads();
    part[t] += add;
    __syncthreads();
  }
  row_ptr[node] = part[t];               // block-local inclusive
  if (t == 1023) bsum[blockIdx.x] = part[1023];
}

// apply block offsets -> exclusive global prefix; zero cursors; total
__global__ __launch_bounds__(1024) void k_scanB(const int* __restrict__ bsum,
                                                int* __restrict__ row_ptr,
                                                int* __restrict__ counts) {
  __shared__ int sb[32];
  int t = threadIdx.x, b = blockIdx.x;
  if (t < 32) sb[t] = bsum[t];
  __syncthreads();
  int boff = 0;
#pragma unroll
  for (int i = 0; i < 32; ++i) boff += (i < b) ? sb[i] : 0;
  int node = b * 1024 + t;
  int incl = row_ptr[node];
  int cnt = counts[node];
  row_ptr[node] = boff + incl - cnt;     // exclusive global prefix
  counts[node] = 0;                      // cursor init for k_fill
  if (b == 31 && t == 1023) {
    int tot = 0;
#pragma unroll
    for (int i = 0; i < 32; ++i) tot += sb[i];
    row_ptr[N_NODES] = tot;
  }
}

__global__ void k_fill(const int* __restrict__ ei, const int* __restrict__ row_ptr,
                       int* __restrict__ cursor, int* __restrict__ srcs) {
  for (int e = blockIdx.x * blockDim.x + threadIdx.x; e < N_EDGES;
       e += gridDim.x * blockDim.x) {
    int d = ei[N_EDGES + e] & NODE_MASK;
    int pos = row_ptr[d] + atomicAdd(&cursor[d], 1);
    srcs[pos] = ei[e] & NODE_MASK;
  }
}

// ---------------- merged prep (blocks 0..767) + lin0 (768..8959) ------------
__global__ __launch_bounds__(256) void k_preplin0(
    const float* __restrict__ G, const float* __restrict__ w_ih,
    const float* __restrict__ w_hh,
    _Float16* __restrict__ WcF, _Float16* __restrict__ whhF,
    float* __restrict__ z,
    const float* __restrict__ x, const float* __restrict__ lw,
    float* __restrict__ hf, _Float16* __restrict__ h16) {
  __shared__ float sw[64][33];
  __shared__ float sx[4][32];
  int b = blockIdx.x, t = threadIdx.x;
  if (b < 768) {
    int i = b * 256 + t;
    if (i < 4 * 384 * 128) {
      int L = i / (384 * 128), r = i % (384 * 128);
      int c = r >> 7, k = r & 127;
      const float* g  = G + L * 16384 + k * 128;
      const float* wv = w_ih + c * 128;
      float acc = 0.f;
#pragma unroll 8
      for (int j = 0; j < 128; ++j) acc += g[j] * wv[j];
      WcF[i] = (_Float16)acc;
    }
    if (i < 384 * 128) whhF[i] = (_Float16)w_hh[i];
    if (i < 32640) {
      uint32_t o0, o1;
      threefry2x32(0u, 123u, 0u, (uint32_t)i, &o0, &o1);
      z[i] = bits_to_normal(o0 ^ o1);
    }
    return;
  }
  // ---- lin0 path ----
  int node0 = (b - 768) * 4;
  for (int e = t; e < 64 * 32; e += 256) sw[e >> 5][e & 31] = lw[e];
  if (t < 128) sx[t >> 5][t & 31] = x[node0 * 32 + t];
  __syncthreads();
  int c = t & 63, nl = t >> 6;
  float acc = 0.f;
#pragma unroll
  for (int k = 0; k < 32; ++k) acc += sx[nl][k] * sw[c][k];
  float s = 1.f / (1.f + expf(-acc));
  int n = node0 + nl;
  hf[n * 128 + c] = s;
  hf[n * 128 + 64 + c] = 0.f;
  h16[n * 128 + c] = (_Float16)s;
  h16[n * 128 + 64 + c] = (_Float16)0.f;
}

// ---------------- segment-sum gather -> f16 mg ------------------------------
// full width: 4 edges x 16 colgroups x 16 B/lane.
// halfw (layer 0: cols 64..127 zero): 8 edges x 8 colgroups.
__global__ void k_agg(const _Float16* __restrict__ h16,
                      _Float16* __restrict__ mg,
                      const int* __restrict__ row_ptr, const int* __restrict__ srcs,
                      int halfw) {
  int wid = (blockIdx.x * blockDim.x + threadIdx.x) >> 6;
  int lane = threadIdx.x & 63;
  if (wid >= N_NODES) return;
  int beg = row_ptr[wid], end = row_ptr[wid + 1];
  float acc[8];
#pragma unroll
  for (int i = 0; i < 8; ++i) acc[i] = 0.f;
  if (!halfw) {
    int cg = lane & 15, eg = lane >> 4;
#pragma unroll 2
    for (int e = beg + eg; e < end; e += 4) {
      int s = srcs[e];
      f16x8 v = *(const f16x8*)&h16[s * 128 + cg * 8];
#pragma unroll
      for (int i = 0; i < 8; ++i) acc[i] += (float)v[i];
    }
#pragma unroll
    for (int i = 0; i < 8; ++i) {
      acc[i] += __shfl_xor(acc[i], 16);
      acc[i] += __shfl_xor(acc[i], 32);
    }
    if (eg == 0) {
      f16x8 o;
#pragma unroll
      for (int i = 0; i < 8; ++i) o[i] = (_Float16)acc[i];
      *(f16x8*)&mg[wid * 128 + cg * 8] = o;
    }
  } else {
    int cg = lane & 7, eg = lane >> 3;
#pragma unroll 2
    for (int e = beg + eg; e < end; e += 8) {
      int s = srcs[e];
      f16x8 v = *(const f16x8*)&h16[s * 128 + cg * 8];
#pragma unroll
      for (int i = 0; i < 8; ++i) acc[i] += (float)v[i];
    }
#pragma unroll
    for (int i = 0; i < 8; ++i) {
      acc[i] += __shfl_xor(acc[i], 8);
      acc[i] += __shfl_xor(acc[i], 16);
      acc[i] += __shfl_xor(acc[i], 32);
    }
    if (eg == 0) {
      f16x8 o, zz;
#pragma unroll
      for (int i = 0; i < 8; ++i) { o[i] = (_Float16)acc[i]; zz[i] = (_Float16)0.f; }
      *(f16x8*)&mg[wid * 128 + cg * 8] = o;
      *(f16x8*)&mg[wid * 128 + 64 + cg * 8] = zz;
    }
  }
}

// ---------------- fused GRU via f16 MFMA (16 nodes/wave) --------------------
// gi = mg(f16) @ Wc^T (+b_ih): single-plane A (mg quantization 2^-11, small
// vs gate scale). gh = h(2-term f16) @ w_hh^T (+b_hh). 9 MFMA per kk.
__global__ __launch_bounds__(256, 2) void k_gru_mfma(
    const _Float16* __restrict__ mg,
    float* __restrict__ hf, _Float16* __restrict__ h16,
    const _Float16* __restrict__ WcF, const _Float16* __restrict__ whhF,
    const float* __restrict__ b_ih, const float* __restrict__ b_hh,
    int writeShadow) {
  __shared__ __align__(16) char smem[24576];  // 6 slices x 4 KB
  int t = threadIdx.x;
  int w = t >> 6, l = t & 63;
  int node0 = blockIdx.x * 64 + w * 16;
  int ar = l & 15, hi = l >> 4, ak = hi * 8;
  f16x8 am[4], ahH[4], ahL[4];
#pragma unroll
  for (int kk = 0; kk < 4; ++kk) {
    int o = (node0 + ar) * 128 + kk * 32 + ak;
    am[kk] = *(const f16x8*)&mg[o];
    split8f(&hf[o], &ahH[kk], &ahL[kk]);
  }
  const _Float16* pq[6];
#pragma unroll
  for (int q = 0; q < 6; ++q) {
    int i = (q * 4 + w) * 64 + l;
    int s = i >> 8, r = (i >> 4) & 15, gl = i & 15;
    int gsrc = gl ^ (r & 7);
    int mtx = s / 3, gate = s % 3;
    const _Float16* base = mtx ? whhF : WcF;
    pq[q] = base + (gate * 128 + r) * 128 + gsrc * 8;
  }
  const char* lds = (const char*)smem;
  for (int ct = 0; ct < 8; ++ct) {
    int c0 = ct * 16;
#pragma unroll
    for (int q = 0; q < 6; ++q) {
      __builtin_amdgcn_global_load_lds(
          (const __attribute__((address_space(1))) void*)(pq[q] + c0 * 128),
          (__attribute__((address_space(3))) void*)(smem + (q * 4 + w) * 1024),
          16, 0, 0);
    }
    int col = c0 + ar;
    float hp[4];
#pragma unroll
    for (int j = 0; j < 4; ++j)
      hp[j] = hf[(node0 + hi * 4 + j) * 128 + col];
    __syncthreads();
    f32x4 air = {0.f,0.f,0.f,0.f}, aiz = air, ain = air;
    f32x4 ahr = air, ahz = air, ahn = air;
    int rbase = ar * 256;
    int rsw = (ar & 7) << 4;
#pragma unroll
    for (int kk = 0; kk < 4; ++kk) {
      int bin = rbase + ((kk * 64 + hi * 16) ^ rsw);
      f16x8 W0 = *(const f16x8*)(lds + 0 * 4096 + bin);
      f16x8 W1 = *(const f16x8*)(lds + 1 * 4096 + bin);
      f16x8 W2 = *(const f16x8*)(lds + 2 * 4096 + bin);
      f16x8 W3 = *(const f16x8*)(lds + 3 * 4096 + bin);
      f16x8 W4 = *(const f16x8*)(lds + 4 * 4096 + bin);
      f16x8 W5 = *(const f16x8*)(lds + 5 * 4096 + bin);
      air = __builtin_amdgcn_mfma_f32_16x16x32_f16(am[kk],  W0, air, 0, 0, 0);
      aiz = __builtin_amdgcn_mfma_f32_16x16x32_f16(am[kk],  W1, aiz, 0, 0, 0);
      ain = __builtin_amdgcn_mfma_f32_16x16x32_f16(am[kk],  W2, ain, 0, 0, 0);
      ahr = __builtin_amdgcn_mfma_f32_16x16x32_f16(ahH[kk], W3, ahr, 0, 0, 0);
      ahr = __builtin_amdgcn_mfma_f32_16x16x32_f16(ahL[kk], W3, ahr, 0, 0, 0);
      ahz = __builtin_amdgcn_mfma_f32_16x16x32_f16(ahH[kk], W4, ahz, 0, 0, 0);
      ahz = __builtin_amdgcn_mfma_f32_16x16x32_f16(ahL[kk], W4, ahz, 0, 0, 0);
      ahn = __builtin_amdgcn_mfma_f32_16x16x32_f16(ahH[kk], W5, ahn, 0, 0, 0);
      ahn = __builtin_amdgcn_mfma_f32_16x16x32_f16(ahL[kk], W5, ahn, 0, 0, 0);
    }
    float bir = b_ih[col], biz = b_ih[128 + col], bin = b_ih[256 + col];
    float bhr = b_hh[col], bhz = b_hh[128 + col], bhn = b_hh[256 + col];
#pragma unroll
    for (int j = 0; j < 4; ++j) {
      int idx = (node0 + hi * 4 + j) * 128 + col;
      float gr = air[j] + bir + ahr[j] + bhr;
      float gz = aiz[j] + biz + ahz[j] + bhz;
      float r  = 1.f / (1.f + expf(-gr));
      float zg = 1.f / (1.f + expf(-gz));
      float nn = tanhf(ain[j] + bin + r * (ahn[j] + bhn));
      float hn = (1.f - zg) * nn + zg * hp[j];
      hf[idx] = hn;
      if (writeShadow) h16[idx] = (_Float16)hn;
    }
    __syncthreads();
  }
}

// ---------------- heads (f32 hf) ---------------------------------------------
__global__ __launch_bounds__(256) void k_musig(const float* __restrict__ hf,
                                               const float* __restrict__ w1,
                                               const float* __restrict__ b1,
                                               const float* __restrict__ w2,
                                               const float* __restrict__ b2,
                                               float* __restrict__ mu,
                                               float* __restrict__ sigma) {
  int t = threadIdx.x;
  int lane = t & 63, wv = t >> 6;
  int n = blockIdx.x * 4 + wv;
  float2 hv = *(const float2*)&hf[n * 128 + lane * 2];
  hv.x = fmaxf(hv.x, 0.f); hv.y = fmaxf(hv.y, 0.f);
  float2 w1v = *(const float2*)&w1[lane * 2];
  float2 w2v = *(const float2*)&w2[lane * 2];
  float a = hv.x * w1v.x + hv.y * w1v.y;
  float b = hv.x * w2v.x + hv.y * w2v.y;
#pragma unroll
  for (int off = 32; off > 0; off >>= 1) {
    a += __shfl_down(a, off);
    b += __shfl_down(b, off);
  }
  if (lane == 0) {
    mu[n] = a + b1[0];
    float v = b + b2[0];
    sigma[n] = fmaxf(v, 0.f) + log1pf(expf(-fabsf(v)));
  }
}

// ---------------- sampler (fp64 internal): analytic Cholesky ----------------
__device__ __forceinline__ double dscan_incl(double v, volatile double* buf, int i,
                                             double* tot) {
  buf[i] = v;
  __syncthreads();
#pragma unroll
  for (int off = 1; off < 256; off <<= 1) {
    double add = (i >= off) ? buf[i - off] : 0.0;
    __syncthreads();
    buf[i] += add;
    __syncthreads();
  }
  double incl = buf[i];
  *tot = buf[255];
  __syncthreads();
  return incl;
}

__global__ __launch_bounds__(256) void k_sample(const float* __restrict__ mu,
                                                const float* __restrict__ sigma,
                                                const float* __restrict__ zbuf,
                                                float* __restrict__ out) {
  __shared__ double buf[256];
  __shared__ double lastd[2];
  int g = blockIdx.x, i = threadIdx.x;
  int n = (g << 8) + i;
  double sig = (double)sigma[n], muv = (double)mu[n];
  bool isLast = (i == 255);
  if (isLast) { lastd[0] = sig; lastd[1] = muv; }
  double s   = isLast ? 0.0 : sig;
  double mui = isLast ? 0.0 : muv;
  double tS, tM, tY, tX;
  double inclS = dscan_incl(s, buf, i, &tS);
  dscan_incl(mui, buf, i, &tM);
  double sigLast = lastd[0], muLast = lastd[1];
  double denom = tS + sigLast;
  double c = -muLast / sigLast;
  double pre = inclS - s;
  double suffix  = denom - pre;
  double suffix1 = suffix - s;
  double sigL = isLast ? 0.0 : sqrt(s * suffix1 / suffix);
  double cL   = isLast ? 0.0 : (-s / (suffix * sigL));
  double zv   = isLast ? 0.0 : (double)zbuf[g * 255 + i];
  double y = cL * zv;
  double inclY = dscan_incl(y, buf, i, &tY);
  double Pz = inclY - y;
  double rm = s * c + mui - s * (c * tS + tM) / denom;
  double X = rm + s * Pz + sigL * zv;
  if (isLast) X = 0.0;
  dscan_incl(X, buf, i, &tX);
  out[n] = (float)(isLast ? (0.0 - tX) : X);
}

// ---------------------------------------------------------------------------
extern "C" void kernel_launch(void* const* d_in, const int* in_sizes, int n_in,
                              void* d_out, int out_size, void* d_ws, size_t ws_size,
                              hipStream_t stream) {
  const float* x      = (const float*)d_in[0];
  const float* lin0_w = (const float*)d_in[1];
  const float* ggc_w  = (const float*)d_in[2];
  const float* w_ih   = (const float*)d_in[3];
  const float* w_hh   = (const float*)d_in[4];
  const float* b_ih   = (const float*)d_in[5];
  const float* b_hh   = (const float*)d_in[6];
  const float* lin1_w = (const float*)d_in[7];
  const float* lin1_b = (const float*)d_in[8];
  const float* lin2_w = (const float*)d_in[9];
  const float* lin2_b = (const float*)d_in[10];
  const int*   ei     = (const int*)d_in[11];
  float* out = (float*)d_out;

  char* ws = (char*)d_ws;
  float*     hf     = (float*)    (ws + 0);          // 16 MB
  _Float16*  h16    = (_Float16*) (ws + 16777216);   // 8 MB
  _Float16*  mg     = (_Float16*) (ws + 25165824);   // 8 MB (f16 hagg)
  _Float16*  WcF    = (_Float16*) (ws + 33554432);   // 384 KB
  _Float16*  whhF   = (_Float16*) (ws + 33947648);   // 96 KB
  float*     zbuf   = (float*)    (ws + 34045952);   // 128 KB [counts aliases]
  float*     mu     = (float*)    (ws + 34177024);   // 128 KB
  float*     sigma  = (float*)    (ws + 34308096);   // 128 KB
  int*       row_ptr= (int*)      (ws + 34439168);   // 128.5 KB slot
  int*       srcs   = (int*)      (ws + 34570752);   // 2 MB
  int*       bsum   = (int*)      (ws + 36667904);   // 128 B
  int*       counts = (int*)zbuf;                    // alias: CSR before k_preplin0
  const size_t WS_NEEDED = 36668032;                 // < proven 53477888
  if (ws_size < WS_NEEDED) return;

  // CSR build (parallel scan; counts re-zeroed by k_scanB for cursor use)
  k_zero<<<32, 256, 0, stream>>>(counts, N_NODES);
  k_hist<<<1024, 256, 0, stream>>>(ei, counts);
  k_scanA<<<32, 1024, 0, stream>>>(counts, row_ptr, bsum);
  k_scanB<<<32, 1024, 0, stream>>>(bsum, row_ptr, counts);
  k_fill<<<1024, 256, 0, stream>>>(ei, row_ptr, counts, srcs);

  k_preplin0<<<8960, 256, 0, stream>>>(ggc_w, w_ih, w_hh, WcF, whhF, zbuf,
                                       x, lin0_w, hf, h16);

  for (int L = 0; L < 4; ++L) {
    k_agg<<<8192, 256, 0, stream>>>(h16, mg, row_ptr, srcs, L == 0 ? 1 : 0);
    k_gru_mfma<<<512, 256, 0, stream>>>(mg, hf, h16,
                                        WcF + (size_t)L * 49152,
                                        whhF, b_ih, b_hh, L < 3 ? 1 : 0);
  }

  k_musig<<<8192, 256, 0, stream>>>(hf, lin1_w, lin1_b, lin2_w, lin2_b, mu, sigma);
  k_sample<<<128, 256, 0, stream>>>(mu, sigma, zbuf, out);
}